// Round 15
// baseline (277.025 us; speedup 1.0000x reference)
//
#include <hip/hip_runtime.h>
#include <hip/hip_bf16.h>
#include <hip/hip_fp8.h>
#include <math.h>

#define M_TOT 4096
#define K_TOT 1024
#define V_TOT 32000

typedef int int4v __attribute__((ext_vector_type(4)));
typedef int int8v __attribute__((ext_vector_type(8)));
typedef float f32x4 __attribute__((ext_vector_type(4)));

__device__ __forceinline__ void gload_lds16(const void* g, void* l) {
  __builtin_amdgcn_global_load_lds(
      (const __attribute__((address_space(1))) void*)g,
      (__attribute__((address_space(3))) void*)l, 16, 0, 0);
}

__device__ __forceinline__ float sani(float v) {
  return (v != v) ? 0.0f : fminf(fmaxf(v, -1e4f), 1e4f);
}

__device__ __forceinline__ int pk4_fp8(float a, float b, float c, float d) {
#if __has_builtin(__builtin_amdgcn_cvt_pk_fp8_f32)
  int p = __builtin_amdgcn_cvt_pk_fp8_f32(a, b, 0, false);
  p = __builtin_amdgcn_cvt_pk_fp8_f32(c, d, p, true);
  return p;
#else
  union { unsigned char b4[4]; int i; } u;
  u.b4[0] = __hip_fp8_e4m3(a).__x;
  u.b4[1] = __hip_fp8_e4m3(b).__x;
  u.b4[2] = __hip_fp8_e4m3(c).__x;
  u.b4[3] = __hip_fp8_e4m3(d).__x;
  return u.i;
#endif
}

// merged prep: blocks [0,4096) do hidden_states, [4096,36096) do weights.
// Block-uniform branch (no wave divergence); lets the tiny h-pass overlap
// the w-pass instead of serializing two launches.
__global__ void prep_hw(const float* __restrict__ h, const float* __restrict__ w,
                        unsigned char* __restrict__ h8, unsigned char* __restrict__ w8,
                        float* __restrict__ h0, float* __restrict__ wtime) {
  __shared__ float red[4];
  __shared__ float r_sh;
  const int b = blockIdx.x;
  const int t = threadIdx.x;
  if (b < M_TOT) {
    const int m = b;
    const float* row = h + (long)m * (K_TOT + 1);
    if (t == 0) h0[m] = sani(row[0]);
    float4 x = *(const float4*)(row + 1 + t * 4);
    ((int*)(h8 + (long)m * K_TOT))[t] =
        pk4_fp8(sani(x.x), sani(x.y), sani(x.z), sani(x.w));
  } else {
    const int v = b - M_TOT;
    const float* row = w + (long)v * K_TOT;
    float4 x = *(const float4*)(row + t * 4);
    float s = x.x * x.x + x.y * x.y + x.z * x.z + x.w * x.w;
#pragma unroll
    for (int off = 32; off > 0; off >>= 1) s += __shfl_down(s, off);
    int lane = t & 63, wv = t >> 6;
    if (lane == 0) red[wv] = s;
    __syncthreads();
    if (t == 0) {
      float tot = red[0] + red[1] + red[2] + red[3];
      float norm = sqrtf(tot);
      float r = (norm > 1e-7f) ? (sinhf(norm) / fmaxf(norm, 1e-7f)) : 1.0f;
      r_sh = r;
      wtime[v] = coshf(norm);
    }
    __syncthreads();
    float sc = 16.0f * r_sh;  // 16x prescale; undone by MFMA scaleA = 2^-4
    ((int*)(w8 + (long)v * K_TOT))[t] =
        pk4_fp8(sc * x.x, sc * x.y, sc * x.z, sc * x.w);
  }
}

// ====== 256x256 tile, BK=128, MX-fp8 double-buffered GEMM (r11+r14) ========
// r14 (best, 273.5us): r11 loop + nontemporal full-line float4 stores.
// This round's ONLY gemm change: L2-fitting grid regroup. Before: 16
// consecutive blocks/XCD shared one B-panel but spanned ALL 16 m-tiles =
// entire 4MB A + panel > 4MB per-XCD L2 -> A thrashed (r11 FETCH 355MB =
// 10x inputs). Now: 8 consecutive blocks share (B-panel 256KB, A-HALF 2MB)
// = 2.25MB, L2-fit with headroom for the transient write stream.
// LDS (128 KB): buf*65536 + {A: row*128 + c*16} + {B: 32768 + row*128 + c*16}
// Zero-conflict swizzle (measured ~0, r11): slot chunk c holds global chunk
// c^(row&7); source pre-swizzled cc=(t&7)^((t>>3)&7); read (2fq+h)^(fr&7).
// Loop: reads -> MFMA m0-3 -> reads av4-7 -> lgkm0+schedbar+BAR -> STAGE
// kt+2 into cb -> MFMA m4-7 -> VM8 (counted; kt+2's 8 stay in flight) -> BAR.
// launch_bounds(512,2): VGPR cap 256 ((512,4) caps 64 -> acc spill -> r4's
// 13.9GB disaster). r13 lesson: smaller tile/2-blocks-per-CU loses (staging
// traffic doubles). r12 lesson: store-interleave in K-loop breaks the
// conflict-free scheduling. Keep this structure.
#define BAR __builtin_amdgcn_s_barrier()
#define LGKM0 asm volatile("s_waitcnt lgkmcnt(0)" ::: "memory")
#define VM8 asm volatile("s_waitcnt vmcnt(8)" ::: "memory")

__global__ __launch_bounds__(512, 2) void gemm_geo(
    const unsigned char* __restrict__ h8, const unsigned char* __restrict__ w8,
    const float* __restrict__ h0, const float* __restrict__ wtime,
    const float* __restrict__ ls, float* __restrict__ out) {
  __shared__ __align__(16) char smem[131072];

  const int t = threadIdx.x;
  const int wave = t >> 6, lane = t & 63;
  const int fr = lane & 15, fq = lane >> 4;
  const int wm = wave >> 2, wn = wave & 3;  // 2 (M) x 4 (N) wave grid

  // XCD-bijective grid: 2000 blocks, 250/XCD (contiguous chunk per XCD).
  // Within an XCD chunk: 8 consecutive blocks = one (v-panel, m-half) group.
  const int bid = blockIdx.x;
  const int swz = (bid & 7) * 250 + (bid >> 3);
  const int tile_v = swz >> 4;                    // [0,125)
  const int mhalf = (swz >> 3) & 1;
  const int tile_m = (swz & 7) + mhalf * 8;       // [0,16)
  const int row0 = tile_m * 256;
  const int col0 = tile_v * 256;

  // read-side lane constants (bytes)
  const int xorv = fr & 7;
  const int c0 = ((2 * fq) ^ xorv) * 16;
  const int c1 = ((2 * fq + 1) ^ xorv) * 16;
  const int a_rd = (wm * 128 + fr) * 128;          // + cbo + im*2048
  const int b_rd = 32768 + (wn * 64 + fr) * 128;   // + cbo + iv*2048

  auto RDF = [&](int off) -> int8v {
    int4v lo = *(const int4v*)(smem + off + c0);
    int4v hi = *(const int4v*)(smem + off + c1);
    return (int8v){lo[0], lo[1], lo[2], lo[3], hi[0], hi[1], hi[2], hi[3]};
  };

  // staging: thread t -> row t>>3 (+64/batch), slot chunk t&7; source chunk
  // pre-swizzled (rule #21: gload_lds writes linearly)
  const int cc = (t & 7) ^ ((t >> 3) & 7);
  const unsigned char* pA = h8 + ((long)row0 + (t >> 3)) * K_TOT + cc * 16;
  const unsigned char* pB = w8 + ((long)col0 + (t >> 3)) * K_TOT + cc * 16;
  const int dst_w = wave * 1024;  // wave-uniform; HW adds lane*16

  auto STAGE = [&](int kt, int bufo) {
#pragma unroll
    for (int hh = 0; hh < 4; ++hh) {
      gload_lds16(pA + (long)hh * 65536 + kt * 128,
                  smem + bufo + hh * 8192 + dst_w);
      gload_lds16(pB + (long)hh * 65536 + kt * 128,
                  smem + bufo + 32768 + hh * 8192 + dst_w);
    }
  };

  f32x4 acc[8][4];
#pragma unroll
  for (int i = 0; i < 8; ++i)
#pragma unroll
    for (int j = 0; j < 4; ++j) acc[i][j] = (f32x4)(0.0f);

  // prologue: tiles 0,1 -> bufs 0,1 (8 loads each); VM8 proves tile0.
  STAGE(0, 0);
  STAGE(1, 65536);
  VM8;
  BAR;

#pragma unroll 1
  for (int kt = 0; kt < 8; ++kt) {
    const int cbo = (kt & 1) << 16;
    const int skt = (kt + 2 < 8) ? kt + 2 : 7;  // clamped redundant tail

    int8v bv[4], av[4];
#pragma unroll
    for (int iv = 0; iv < 4; ++iv) bv[iv] = RDF(cbo + b_rd + iv * 2048);
#pragma unroll
    for (int im = 0; im < 4; ++im) av[im] = RDF(cbo + a_rd + im * 2048);

    __builtin_amdgcn_s_setprio(1);
#pragma unroll
    for (int im = 0; im < 4; ++im)
#pragma unroll
      for (int iv = 0; iv < 4; ++iv)
        acc[im][iv] = __builtin_amdgcn_mfma_scale_f32_16x16x128_f8f6f4(
            bv[iv], av[im], acc[im][iv], 0, 0, 0, 0x7B7B7B7B, 0, 0x7F7F7F7F);
    __builtin_amdgcn_s_setprio(0);

    int8v av2[4];
#pragma unroll
    for (int im = 0; im < 4; ++im)
      av2[im] = RDF(cbo + a_rd + (4 + im) * 2048);
    LGKM0;
    __builtin_amdgcn_sched_barrier(0);
    BAR;  // all waves done reading buf cbo -> safe to overwrite it

    STAGE(skt, cbo);  // tile kt+2 -> same-parity buffer (double buffer)

    __builtin_amdgcn_s_setprio(1);
#pragma unroll
    for (int im = 0; im < 4; ++im)
#pragma unroll
      for (int iv = 0; iv < 4; ++iv)
        acc[4 + im][iv] = __builtin_amdgcn_mfma_scale_f32_16x16x128_f8f6f4(
            bv[iv], av2[im], acc[4 + im][iv], 0, 0, 0, 0x7B7B7B7B, 0,
            0x7F7F7F7F);
    __builtin_amdgcn_s_setprio(0);

    // proves tile kt+1 landed (its 8 loads are >=8 back; kt+2's 8 in flight)
    VM8;
    BAR;
  }

  // fused epilogue: x = h0*w_time - dot; d2 = acosh(x)^2; out = -tau*d2.
  // v on acc-reg axis -> float4 nontemporal stores (full 64B lines: 4 lanes
  // x 16B contiguous) keep the 512MB write stream out of L2 (r14: -17us).
  const float ntau = -fminf(fmaxf(ls[0], 0.01f), 2.5f);
  const float LN2 = 0.69314718055994531f;
  f32x4 wt4[4];
#pragma unroll
  for (int iv = 0; iv < 4; ++iv)
    wt4[iv] = *(const f32x4*)&wtime[col0 + wn * 64 + iv * 16 + fq * 4];
#pragma unroll
  for (int im = 0; im < 8; ++im) {
    const float hh = h0[row0 + wm * 128 + im * 16 + fr];
    float* orow =
        out + (long)(row0 + wm * 128 + im * 16 + fr) * V_TOT + col0 + wn * 64;
#pragma unroll
    for (int iv = 0; iv < 4; ++iv) {
      f32x4 r;
#pragma unroll
      for (int j = 0; j < 4; ++j) {
        float x = fmaf(hh, wt4[iv][j], -acc[im][iv][j]);
        float xm1 = fmaxf(x - 1.0f, 0.0f);
        float arg = fmaxf(fmaf(x, x, -1.0f), 0.0f);
        float lg2 = __builtin_amdgcn_logf(x + __builtin_amdgcn_sqrtf(arg));
        float dex = LN2 * lg2;
        float d2_exact = dex * dex;
        float ts = fmaf(xm1, -1.0f / 12.0f, 1.0f);
        float d2_tay = 2.0f * xm1 * ts * ts;
        float d2 = (xm1 < 1e-3f) ? d2_tay : d2_exact;
        r[j] = ntau * d2;
      }
      __builtin_nontemporal_store(r, (f32x4*)(orow + iv * 16 + fq * 4));
    }
  }
}

extern "C" void kernel_launch(void* const* d_in, const int* in_sizes, int n_in,
                              void* d_out, int out_size, void* d_ws, size_t ws_size,
                              hipStream_t stream) {
  const float* h = (const float*)d_in[0];   // [2,2048,1025]
  const float* w = (const float*)d_in[1];   // [32000,1024]
  const float* ls = (const float*)d_in[2];  // scalar
  float* out = (float*)d_out;               // [2,2048,32000] fp32

  char* ws = (char*)d_ws;
  unsigned char* w8 = (unsigned char*)ws;                     // 32,768,000 B
  unsigned char* h8 = (unsigned char*)(ws + 32768000);        // 4,194,304 B
  float* wtime = (float*)(ws + 32768000 + 4194304);           // 128,000 B
  float* h0 = (float*)(ws + 32768000 + 4194304 + 128000);     // 16,384 B

  prep_hw<<<M_TOT + V_TOT, 256, 0, stream>>>(h, w, h8, w8, h0, wtime);
  gemm_geo<<<2000, 512, 0, stream>>>(h8, w8, h0, wtime, ls, out);
}

// Round 16
// 271.716 us; speedup vs baseline: 1.0195x; 1.0195x over previous
//
#include <hip/hip_runtime.h>
#include <hip/hip_bf16.h>
#include <hip/hip_fp8.h>
#include <math.h>

#define M_TOT 4096
#define K_TOT 1024
#define V_TOT 32000

typedef int int4v __attribute__((ext_vector_type(4)));
typedef int int8v __attribute__((ext_vector_type(8)));
typedef float f32x4 __attribute__((ext_vector_type(4)));

__device__ __forceinline__ void gload_lds16(const void* g, void* l) {
  __builtin_amdgcn_global_load_lds(
      (const __attribute__((address_space(1))) void*)g,
      (__attribute__((address_space(3))) void*)l, 16, 0, 0);
}

__device__ __forceinline__ float sani(float v) {
  return (v != v) ? 0.0f : fminf(fmaxf(v, -1e4f), 1e4f);
}

__device__ __forceinline__ int pk4_fp8(float a, float b, float c, float d) {
#if __has_builtin(__builtin_amdgcn_cvt_pk_fp8_f32)
  int p = __builtin_amdgcn_cvt_pk_fp8_f32(a, b, 0, false);
  p = __builtin_amdgcn_cvt_pk_fp8_f32(c, d, p, true);
  return p;
#else
  union { unsigned char b4[4]; int i; } u;
  u.b4[0] = __hip_fp8_e4m3(a).__x;
  u.b4[1] = __hip_fp8_e4m3(b).__x;
  u.b4[2] = __hip_fp8_e4m3(c).__x;
  u.b4[3] = __hip_fp8_e4m3(d).__x;
  return u.i;
#endif
}

// merged prep: blocks [0,4096) do hidden_states, [4096,36096) do weights.
__global__ void prep_hw(const float* __restrict__ h, const float* __restrict__ w,
                        unsigned char* __restrict__ h8, unsigned char* __restrict__ w8,
                        float* __restrict__ h0, float* __restrict__ wtime) {
  __shared__ float red[4];
  __shared__ float r_sh;
  const int b = blockIdx.x;
  const int t = threadIdx.x;
  if (b < M_TOT) {
    const int m = b;
    const float* row = h + (long)m * (K_TOT + 1);
    if (t == 0) h0[m] = sani(row[0]);
    float4 x = *(const float4*)(row + 1 + t * 4);
    ((int*)(h8 + (long)m * K_TOT))[t] =
        pk4_fp8(sani(x.x), sani(x.y), sani(x.z), sani(x.w));
  } else {
    const int v = b - M_TOT;
    const float* row = w + (long)v * K_TOT;
    float4 x = *(const float4*)(row + t * 4);
    float s = x.x * x.x + x.y * x.y + x.z * x.z + x.w * x.w;
#pragma unroll
    for (int off = 32; off > 0; off >>= 1) s += __shfl_down(s, off);
    int lane = t & 63, wv = t >> 6;
    if (lane == 0) red[wv] = s;
    __syncthreads();
    if (t == 0) {
      float tot = red[0] + red[1] + red[2] + red[3];
      float norm = sqrtf(tot);
      float r = (norm > 1e-7f) ? (sinhf(norm) / fmaxf(norm, 1e-7f)) : 1.0f;
      r_sh = r;
      wtime[v] = coshf(norm);
    }
    __syncthreads();
    float sc = 16.0f * r_sh;  // 16x prescale; undone by MFMA scaleA = 2^-4
    ((int*)(w8 + (long)v * K_TOT))[t] =
        pk4_fp8(sc * x.x, sc * x.y, sc * x.z, sc * x.w);
  }
}

// ====== 256x256 tile, BK=128, MX-fp8 double-buffered GEMM ==================
// r14/r15 base. This round's ONLY change: epilogue computes all 4 f32x4
// results per row FIRST, then issues the 4 nt stores BACK-TO-BACK. r15
// counters showed WRITE=744MB (1.45x ideal): L2 lines are 128B, each store
// covers 64B, and the line-completing partner store was ~48 VALU instrs
// away -> outside the write-combine window -> partial-line nt writes (RMW
// amplification). Adjacent stores within a few cycles merge into full
// 128B lines (iv0+1 -> line0, iv2+3 -> line1).
// Kept: L2-fit grid regroup (r15: FETCH 355->151MB; 8 consecutive blocks
// share B-panel 256KB + A-half 2MB = 2.25MB < 4MB/XCD L2), nt stores (r14:
// -17us), zero-conflict swizzle, counted VM8 ledger, lgkm0+BAR
// write-after-read fence, launch_bounds(512,2) (r4: tighter cap -> acc
// spill -> 13.9GB disaster), 256^2 tile at 1 block/CU (r13: 128^2 loses).
#define BAR __builtin_amdgcn_s_barrier()
#define LGKM0 asm volatile("s_waitcnt lgkmcnt(0)" ::: "memory")
#define VM8 asm volatile("s_waitcnt vmcnt(8)" ::: "memory")

__global__ __launch_bounds__(512, 2) void gemm_geo(
    const unsigned char* __restrict__ h8, const unsigned char* __restrict__ w8,
    const float* __restrict__ h0, const float* __restrict__ wtime,
    const float* __restrict__ ls, float* __restrict__ out) {
  __shared__ __align__(16) char smem[131072];

  const int t = threadIdx.x;
  const int wave = t >> 6, lane = t & 63;
  const int fr = lane & 15, fq = lane >> 4;
  const int wm = wave >> 2, wn = wave & 3;  // 2 (M) x 4 (N) wave grid

  // XCD-bijective grid: 2000 blocks, 250/XCD; 8 consecutive blocks per XCD
  // share one (v-panel, m-half) group (L2-fit working set).
  const int bid = blockIdx.x;
  const int swz = (bid & 7) * 250 + (bid >> 3);
  const int tile_v = swz >> 4;                    // [0,125)
  const int mhalf = (swz >> 3) & 1;
  const int tile_m = (swz & 7) + mhalf * 8;       // [0,16)
  const int row0 = tile_m * 256;
  const int col0 = tile_v * 256;

  // read-side lane constants (bytes)
  const int xorv = fr & 7;
  const int c0 = ((2 * fq) ^ xorv) * 16;
  const int c1 = ((2 * fq + 1) ^ xorv) * 16;
  const int a_rd = (wm * 128 + fr) * 128;          // + cbo + im*2048
  const int b_rd = 32768 + (wn * 64 + fr) * 128;   // + cbo + iv*2048

  auto RDF = [&](int off) -> int8v {
    int4v lo = *(const int4v*)(smem + off + c0);
    int4v hi = *(const int4v*)(smem + off + c1);
    return (int8v){lo[0], lo[1], lo[2], lo[3], hi[0], hi[1], hi[2], hi[3]};
  };

  // staging: thread t -> row t>>3 (+64/batch), slot chunk t&7; source chunk
  // pre-swizzled (rule #21: gload_lds writes linearly)
  const int cc = (t & 7) ^ ((t >> 3) & 7);
  const unsigned char* pA = h8 + ((long)row0 + (t >> 3)) * K_TOT + cc * 16;
  const unsigned char* pB = w8 + ((long)col0 + (t >> 3)) * K_TOT + cc * 16;
  const int dst_w = wave * 1024;  // wave-uniform; HW adds lane*16

  auto STAGE = [&](int kt, int bufo) {
#pragma unroll
    for (int hh = 0; hh < 4; ++hh) {
      gload_lds16(pA + (long)hh * 65536 + kt * 128,
                  smem + bufo + hh * 8192 + dst_w);
      gload_lds16(pB + (long)hh * 65536 + kt * 128,
                  smem + bufo + 32768 + hh * 8192 + dst_w);
    }
  };

  f32x4 acc[8][4];
#pragma unroll
  for (int i = 0; i < 8; ++i)
#pragma unroll
    for (int j = 0; j < 4; ++j) acc[i][j] = (f32x4)(0.0f);

  // prologue: tiles 0,1 -> bufs 0,1 (8 loads each); VM8 proves tile0.
  STAGE(0, 0);
  STAGE(1, 65536);
  VM8;
  BAR;

#pragma unroll 1
  for (int kt = 0; kt < 8; ++kt) {
    const int cbo = (kt & 1) << 16;
    const int skt = (kt + 2 < 8) ? kt + 2 : 7;  // clamped redundant tail

    int8v bv[4], av[4];
#pragma unroll
    for (int iv = 0; iv < 4; ++iv) bv[iv] = RDF(cbo + b_rd + iv * 2048);
#pragma unroll
    for (int im = 0; im < 4; ++im) av[im] = RDF(cbo + a_rd + im * 2048);

    __builtin_amdgcn_s_setprio(1);
#pragma unroll
    for (int im = 0; im < 4; ++im)
#pragma unroll
      for (int iv = 0; iv < 4; ++iv)
        acc[im][iv] = __builtin_amdgcn_mfma_scale_f32_16x16x128_f8f6f4(
            bv[iv], av[im], acc[im][iv], 0, 0, 0, 0x7B7B7B7B, 0, 0x7F7F7F7F);
    __builtin_amdgcn_s_setprio(0);

    int8v av2[4];
#pragma unroll
    for (int im = 0; im < 4; ++im)
      av2[im] = RDF(cbo + a_rd + (4 + im) * 2048);
    LGKM0;
    __builtin_amdgcn_sched_barrier(0);
    BAR;  // all waves done reading buf cbo -> safe to overwrite it

    STAGE(skt, cbo);  // tile kt+2 -> same-parity buffer (double buffer)

    __builtin_amdgcn_s_setprio(1);
#pragma unroll
    for (int im = 0; im < 4; ++im)
#pragma unroll
      for (int iv = 0; iv < 4; ++iv)
        acc[4 + im][iv] = __builtin_amdgcn_mfma_scale_f32_16x16x128_f8f6f4(
            bv[iv], av2[im], acc[4 + im][iv], 0, 0, 0, 0x7B7B7B7B, 0,
            0x7F7F7F7F);
    __builtin_amdgcn_s_setprio(0);

    // proves tile kt+1 landed (its 8 loads are >=8 back; kt+2's 8 in flight)
    VM8;
    BAR;
  }

  // fused epilogue: x = h0*w_time - dot; d2 = acosh(x)^2; out = -tau*d2.
  // Compute ALL 4 f32x4 results per row, then 4 nt stores back-to-back so
  // adjacent 64B chunks merge into full 128B L2-lines (fixes r15's 1.45x
  // write amplification).
  const float ntau = -fminf(fmaxf(ls[0], 0.01f), 2.5f);
  const float LN2 = 0.69314718055994531f;
  f32x4 wt4[4];
#pragma unroll
  for (int iv = 0; iv < 4; ++iv)
    wt4[iv] = *(const f32x4*)&wtime[col0 + wn * 64 + iv * 16 + fq * 4];
#pragma unroll
  for (int im = 0; im < 8; ++im) {
    const float hh = h0[row0 + wm * 128 + im * 16 + fr];
    float* orow =
        out + (long)(row0 + wm * 128 + im * 16 + fr) * V_TOT + col0 + wn * 64;
    f32x4 rv[4];
#pragma unroll
    for (int iv = 0; iv < 4; ++iv) {
#pragma unroll
      for (int j = 0; j < 4; ++j) {
        float x = fmaf(hh, wt4[iv][j], -acc[im][iv][j]);
        float xm1 = fmaxf(x - 1.0f, 0.0f);
        float arg = fmaxf(fmaf(x, x, -1.0f), 0.0f);
        float lg2 = __builtin_amdgcn_logf(x + __builtin_amdgcn_sqrtf(arg));
        float dex = LN2 * lg2;
        float d2_exact = dex * dex;
        float ts = fmaf(xm1, -1.0f / 12.0f, 1.0f);
        float d2_tay = 2.0f * xm1 * ts * ts;
        float d2 = (xm1 < 1e-3f) ? d2_tay : d2_exact;
        rv[iv][j] = ntau * d2;
      }
    }
    __builtin_nontemporal_store(rv[0], (f32x4*)(orow + 0 * 16 + fq * 4));
    __builtin_nontemporal_store(rv[1], (f32x4*)(orow + 1 * 16 + fq * 4));
    __builtin_nontemporal_store(rv[2], (f32x4*)(orow + 2 * 16 + fq * 4));
    __builtin_nontemporal_store(rv[3], (f32x4*)(orow + 3 * 16 + fq * 4));
  }
}

extern "C" void kernel_launch(void* const* d_in, const int* in_sizes, int n_in,
                              void* d_out, int out_size, void* d_ws, size_t ws_size,
                              hipStream_t stream) {
  const float* h = (const float*)d_in[0];   // [2,2048,1025]
  const float* w = (const float*)d_in[1];   // [32000,1024]
  const float* ls = (const float*)d_in[2];  // scalar
  float* out = (float*)d_out;               // [2,2048,32000] fp32

  char* ws = (char*)d_ws;
  unsigned char* w8 = (unsigned char*)ws;                     // 32,768,000 B
  unsigned char* h8 = (unsigned char*)(ws + 32768000);        // 4,194,304 B
  float* wtime = (float*)(ws + 32768000 + 4194304);           // 128,000 B
  float* h0 = (float*)(ws + 32768000 + 4194304 + 128000);     // 16,384 B

  prep_hw<<<M_TOT + V_TOT, 256, 0, stream>>>(h, w, h8, w8, h0, wtime);
  gemm_geo<<<2000, 512, 0, stream>>>(h8, w8, h0, wtime, ls, out);
}